// Round 9
// baseline (129.863 us; speedup 1.0000x reference)
//
#include <hip/hip_runtime.h>

typedef unsigned short u16;
typedef _Float16 f16;

#define CIN   64
#define HH    128
#define WW    128
#define NPIX  16384   /* HH*WW */
#define HID   256
#define MTOT  512     /* coef(256) + freq(256) stacked */
#define KTOT  576     /* 64 ch * 9 taps */
#define NB    4
#define WELEM 294912  /* MTOT*KTOT */
#define XROW  130     /* padded input grid row */
#define XROWS 16900   /* 130*130 rows per batch */

/* index-path constants: must bit-match the f32 trace of the reference */
#define SHM  ((float)(-0.0078125 + 1e-6))
#define SHP  ((float)( 0.0078125 + 1e-6))
#define CLO  ((float)(-1.0 + 1e-6))
#define CHI  ((float)( 1.0 - 1e-6))
#define PIF  3.14159265358979323846f

#define QSCL  1024.0f          /* int16 fixed-point scale for YT */
#define QISCL (1.0f / 1024.0f)

using f32x4 = __attribute__((ext_vector_type(4))) float;
using f16x8 = __attribute__((ext_vector_type(8))) _Float16;

/* ---- async global->LDS DMA, 16B per lane (dest = wave base + lane*16) ---- */
typedef __attribute__((address_space(1))) const void gas_void;
typedef __attribute__((address_space(3))) void las_void;
__device__ __forceinline__ void gload16(const void* g, void* l) {
  __builtin_amdgcn_global_load_lds((gas_void*)g, (las_void*)l, 16, 0, 0);
}

/* ---- int16 fixed-point YT helpers ---- */
__device__ __forceinline__ float ldq(const short* p) { return (float)(*p) * QISCL; }
__device__ __forceinline__ void ldqpair(const short* p, float& a, float& b) {
  int u = *(const int*)p;
  a = (float)((short)(u & 0xFFFF)) * QISCL;
  b = (float)((short)(u >> 16)) * QISCL;
}
__device__ __forceinline__ unsigned packq(float a, float b) {
  float fa = fminf(fmaxf(a * QSCL, -32767.f), 32767.f);
  float fb = fminf(fmaxf(b * QSCL, -32767.f), 32767.f);
  int ia = (int)rintf(fa), ib = (int)rintf(fb);
  return ((unsigned)(unsigned short)(short)ia) | (((unsigned)(unsigned short)(short)ib) << 16);
}
__device__ __forceinline__ void storeq4(short* p, float a, float b, float c, float d) {
  uint2 v; v.x = packq(a, b); v.y = packq(c, d);
  *(uint2*)p = v;
}

/* =====================================================================
 * Kernel 1: repack conv weights -> fp16, pre-tiled per (m-half, tap) for
 * 256-row A tiles, chunk-XOR-swizzled by (row&7):
 * Awp[((mt*9+s)*256 + i)*64 + j*8 + e] = W[mt*256+i][((j^(i&7))*8+e][tap s]
 * ===================================================================== */
__global__ __launch_bounds__(256) void lte_prep_w(
    const float* __restrict__ cw, const float* __restrict__ fw,
    f16* __restrict__ Awp) {
  int id = blockIdx.x * 256 + threadIdx.x;
  if (id >= WELEM) return;
  int e  = id & 7;
  int j  = (id >> 3) & 7;
  int i  = (id >> 6) & 255;
  int t2 = id >> 14;            /* mt*9 + s, 0..17 */
  int mt = t2 / 9;
  int s  = t2 - mt * 9;
  int ch = ((j ^ (i & 7)) << 3) + e;
  const float* src = (mt == 0) ? cw : fw;
  Awp[id] = (f16)src[i * KTOT + ch * 9 + s];
}

/* =====================================================================
 * Kernel 1b: input NCHW f32 -> zero-guard-padded pixel-major fp16
 * xp[b][130][130][64], with 16B chunks XOR-permuted by (padded_col & 7)
 * so the GEMM's tap-shifted B fragment reads are bank-conflict-free.
 * ===================================================================== */
__global__ __launch_bounds__(256) void lte_prep_x(
    const float* __restrict__ inp, f16* __restrict__ xp) {
  int id = blockIdx.x * 256 + threadIdx.x;   /* padded row id, NB*16900 */
  if (id >= NB * XROWS) return;
  int b  = id / XROWS;
  int rr = id - b * XROWS;
  int yy = rr / XROW;
  int pc = rr - yy * XROW;      /* padded col 0..129 */
  int x  = pc - 1;
  int y  = yy - 1;
  f16* op = xp + (size_t)id * 64;
  if ((unsigned)y < 128u && (unsigned)x < 128u) {
    const float* ip = inp + (size_t)b * CIN * NPIX + y * WW + x;
    const int p7 = pc & 7;
#pragma unroll
    for (int q = 0; q < 8; ++q) {
      f16x8 v;
#pragma unroll
      for (int k = 0; k < 8; ++k) v[k] = (f16)ip[(((q ^ p7) << 3) + k) * NPIX];
      *(f16x8*)(op + q * 8) = v;
    }
  } else {
    f16x8 z = {};
#pragma unroll
    for (int q = 0; q < 8; ++q) *(f16x8*)(op + q * 8) = z;
  }
}

/* =====================================================================
 * Kernel 2: implicit-im2col GEMM, 256x256 block tile, 8 waves (4M x 2N),
 * wave tile 64x128 (af4 + bg8 per ks -> 42.7 FLOP/LDS-byte: MFMA-bound).
 * Conv-specific: B (4 padded image rows, 68KB) staged ONCE in prologue;
 * taps read it with (ky,kx) shifts. K-loop stages only A (32KB/step,
 * dbuf, issue-early/drain-late). All DMA linear-dest; XOR-chunk swizzle
 * baked into global sources; reads XOR by matching key.
 * Output pixel-major int16 YT[b][p][512] (+bias), scale 1024.
 * ===================================================================== */
__global__ __launch_bounds__(512, 2) void lte_conv_gemm(
    const f16* __restrict__ xp, const f16* __restrict__ Awp,
    const float* __restrict__ coef_b, const float* __restrict__ freq_b,
    short* __restrict__ YT) {
  __shared__ f16 As[2][256 * 64];     /* 2 x 32 KB */
  __shared__ f16 Bs[4 * 136 * 64];    /* 68 KB: 4 padded rows, 136-px pitch */

  const int t  = threadIdx.x;
  const int bx = blockIdx.x;     /* image rows 2bx, 2bx+1 */
  const int mt = blockIdx.y;     /* m half: 0=coef, 1=freq */
  const int bb = blockIdx.z;     /* batch */
  const int l  = t & 63;
  const int w  = t >> 6;         /* 0..7 */
  const int wr = w >> 1;         /* 0..3 (M) */
  const int wc = w & 1;          /* 0..1 (N) */
  const int lm = l & 15;
  const int lm7 = lm & 7;
  const int kq = l >> 4;         /* fragment k-chunk 0..3 */
  const int w4 = w * 4;

  f32x4 acc[4][8] = {};

  const f16* Atile = Awp + (size_t)(mt * 9) * 16384;
  const f16* xb = xp + (size_t)bb * XROWS * 64;

  /* ---- prologue: stage B rows 2bx-1..2bx+2 (padded idx 2bx..2bx+3),
     68 x 1KB calls; + A step 0 (32 calls) ---- */
  {
    const int yp0 = 2 * bx;
    for (int c = w; c < 68; c += 8) {
      const int rr = c / 17, cc = c - rr * 17;
      gload16(xb + (size_t)((yp0 + rr) * XROW + cc * 8) * 64 + l * 8,
              Bs + (rr * 136 + cc * 8) * 64);
    }
#pragma unroll
    for (int i = 0; i < 4; ++i) {
      const int c = w4 + i;
      gload16(Atile + c * 512 + l * 8, As[0] + c * 512);
    }
  }
  asm volatile("s_waitcnt vmcnt(0)" ::: "memory");
  __builtin_amdgcn_s_barrier();
  __builtin_amdgcn_sched_barrier(0);

  for (int s = 0; s < 9; ++s) {
    const int cur = s & 1;
    if (s < 8) {                        /* issue-early A prefetch */
      const f16* asrc = Atile + (s + 1) * 16384;
      f16* Ad = As[cur ^ 1];
#pragma unroll
      for (int i = 0; i < 4; ++i) {
        const int c = w4 + i;
        gload16(asrc + c * 512 + l * 8, Ad + c * 512);
      }
    }
    const int ky = s / 3, kx = s - 3 * (s / 3);
    const f16* Ac = As[cur];
#pragma unroll
    for (int ks = 0; ks < 2; ++ks) {
      const int jl = ks * 4 + kq;
      const int pa = (jl ^ lm7) << 3;
      f16x8 af[4], bg[8];
#pragma unroll
      for (int mi = 0; mi < 4; ++mi)
        af[mi] = *(const f16x8*)&Ac[(wr * 64 + mi * 16 + lm) * 64 + pa];
#pragma unroll
      for (int ni = 0; ni < 8; ++ni) {
        const int n  = wc * 128 + ni * 16 + lm;
        const int rr = (n >> 7) + ky;
        const int xc = (n & 127) + kx;
        bg[ni] = *(const f16x8*)&Bs[(rr * 136 + xc) * 64 + ((jl ^ (xc & 7)) << 3)];
      }
#pragma unroll
      for (int mi = 0; mi < 4; ++mi)
#pragma unroll
        for (int ni = 0; ni < 8; ++ni)
          acc[mi][ni] = __builtin_amdgcn_mfma_f32_16x16x32_f16(af[mi], bg[ni], acc[mi][ni], 0, 0, 0);
    }
    if (s < 8) {                        /* drain-late: hidden under MFMAs */
      asm volatile("s_waitcnt vmcnt(0)" ::: "memory");
      __builtin_amdgcn_s_barrier();
      __builtin_amdgcn_sched_barrier(0);
    }
  }

  /* epilogue: +bias, quantize, store pixel-major YT[b][p][512] */
  const float* bias = (mt == 0) ? coef_b : freq_b;
  const int rj = kq * 4;
#pragma unroll
  for (int mi = 0; mi < 4; ++mi) {
    const int bm = wr * 64 + mi * 16 + rj;          /* 0..255 */
    const float b0 = bias[bm], b1 = bias[bm + 1], b2 = bias[bm + 2], b3 = bias[bm + 3];
#pragma unroll
    for (int ni = 0; ni < 8; ++ni) {
      const int n = wc * 128 + ni * 16 + lm;
      const int p = bx * 256 + n;
      size_t off = ((size_t)(bb * NPIX + p)) * 512 + mt * 256 + bm;
      f32x4 v = acc[mi][ni];
      storeq4(&YT[off], v[0] + b0, v[1] + b1, v[2] + b2, v[3] + b3);
    }
  }
}

/* =====================================================================
 * Kernel 3: 4-corner nearest sample + sin/cos modulation (int16 YT).
 * Validated bit-exact index path — unchanged.
 * ===================================================================== */
__global__ __launch_bounds__(128) void lte_sample(
    const short* __restrict__ YT, const float* __restrict__ coord,
    const float* __restrict__ cell, const float* __restrict__ phase_w,
    float* __restrict__ out) {
  __shared__ float lout[256 * 17];
  const int j     = threadIdx.x;          /* 0..127 */
  const int q0    = blockIdx.x * 16;      /* global over B*Q */
  const int b     = q0 >> 14;
  const int q0loc = q0 & (NPIX - 1);
  const float pw0 = phase_w[2 * j], pw1 = phase_w[2 * j + 1];
  const short* Yb = YT + ((size_t)b * NPIX) * 512;

  for (int qi = 0; qi < 16; ++qi) {
    const int qg = q0 + qi;
    const float c0  = coord[2 * qg], c1 = coord[2 * qg + 1];
    const float ce0 = cell[2 * qg],  ce1 = cell[2 * qg + 1];
    const float ph  = (ce0 * 128.0f) * pw0 + (ce1 * 128.0f) * pw1;
    float accC = 0.f, accS = 0.f, tot = 0.f, a3 = 0.f;
#pragma unroll
    for (int ci = 0; ci < 4; ++ci) {     /* (vx,vy): (-,-),(-,+),(+,-),(+,+) */
      const float s0 = (ci & 2) ? SHP : SHM;
      const float s1 = (ci & 1) ? SHP : SHM;
      float cx = fminf(fmaxf(c0 + s0, CLO), CHI);
      float cy = fminf(fmaxf(c1 + s1, CLO), CHI);
      float ty = ((cx + 1.0f) * 128.0f - 1.0f) * 0.5f;
      float tx = ((cy + 1.0f) * 128.0f - 1.0f) * 0.5f;
      float fy = fminf(fmaxf(rintf(ty), 0.f), 127.f);   /* round half-even */
      float fx = fminf(fmaxf(rintf(tx), 0.f), 127.f);
      int iy = (int)fy, ix = (int)fx;
      float qcy = -1.0f + (2.0f * fy + 1.0f) * (1.0f / 128.0f);
      float qcx = -1.0f + (2.0f * fx + 1.0f) * (1.0f / 128.0f);
      float rel0 = (c0 - qcy) * 128.0f;
      float rel1 = (c1 - qcx) * 128.0f;
      float ar = fabsf(rel0 * rel1);
      tot += ar + 1e-9f;
      if (ci == 3) a3 = ar;
      const short* bp = Yb + ((size_t)(iy * 128 + ix)) * 512;
      float coefA = ldq(bp + j);          /* coef channel j    */
      float coefB = ldq(bp + 128 + j);    /* coef channel j+128 */
      float f0, f1;
      ldqpair(bp + 256 + 2 * j, f0, f1);  /* freq pair (2j,2j+1) */
      float f = f0 * rel0 + f1 * rel1 + ph;
      float ang = PIF * f;
      accC += coefA * __cosf(ang);
      accS += coefB * __sinf(ang);
    }
    const float wgt = a3 / tot;
    lout[j * 17 + qi]         = accC * wgt;
    lout[(j + 128) * 17 + qi] = accS * wgt;
  }
  __syncthreads();
#pragma unroll
  for (int pass = 0; pass < 8; ++pass) {
    int c  = pass * 32 + (j >> 2);
    int qf = (j & 3) * 4;
    float4 v;
    v.x = lout[c * 17 + qf];     v.y = lout[c * 17 + qf + 1];
    v.z = lout[c * 17 + qf + 2]; v.w = lout[c * 17 + qf + 3];
    *(float4*)(out + (((size_t)(b * 256 + c)) << 14) + q0loc + qf) = v;
  }
}

extern "C" void kernel_launch(void* const* d_in, const int* in_sizes, int n_in,
                              void* d_out, int out_size, void* d_ws, size_t ws_size,
                              hipStream_t stream) {
  const float* inp     = (const float*)d_in[0];
  const float* coord   = (const float*)d_in[1];
  const float* cell    = (const float*)d_in[2];
  const float* coef_w  = (const float*)d_in[3];
  const float* coef_b  = (const float*)d_in[4];
  const float* freq_w  = (const float*)d_in[5];
  const float* freq_b  = (const float*)d_in[6];
  const float* phase_w = (const float*)d_in[7];
  float* out = (float*)d_out;

  /* ws: Awp fp16 (0.59MB) | xp_pad fp16 (8.65MB + 1KB DMA slack) | YT int16 (67MB) */
  f16* Awp = (f16*)d_ws;
  f16* xp  = (f16*)((char*)d_ws + (size_t)WELEM * 2);
  short* YT = (short*)((char*)d_ws + (size_t)WELEM * 2
                       + ((size_t)NB * XROWS + 8) * 64 * 2);

  lte_prep_w<<<dim3(1152), dim3(256), 0, stream>>>(coef_w, freq_w, Awp);
  lte_prep_x<<<dim3((NB * XROWS + 255) / 256), dim3(256), 0, stream>>>(inp, xp);
  lte_conv_gemm<<<dim3(64, 2, 4), dim3(512), 0, stream>>>(xp, Awp, coef_b, freq_b, YT);
  lte_sample<<<dim3(4096), dim3(128), 0, stream>>>(YT, coord, cell, phase_w, out);
}